// Round 16
// baseline (664.847 us; speedup 1.0000x reference)
//
#include <hip/hip_runtime.h>
#include <math.h>

#define NN 512
#define EMBD 10
#define HH 64
#define DINV 2
#define CIN 66
#define TT 12
#define BB 16
#define LH 130
#define LG 520
#define PART ((size_t)BB * NN * CIN)

typedef __attribute__((ext_vector_type(8))) short short8;
typedef __attribute__((ext_vector_type(8))) _Float16 half8;
typedef __attribute__((ext_vector_type(4))) float f32x4;
typedef __attribute__((ext_vector_type(2))) _Float16 h2v;

__device__ __forceinline__ float sigmoidf_(float x) { return 1.f / (1.f + __expf(-x)); }
__device__ __forceinline__ float tanhf_(float x)    { return 1.f - 2.f / (1.f + __expf(2.f * x)); }
__device__ __forceinline__ unsigned short f16u_(float v) {
    return __builtin_bit_cast(unsigned short, (_Float16)v);
}
__device__ __forceinline__ unsigned pkh_(float a, float b) {
    return (unsigned)f16u_(a) | ((unsigned)f16u_(b) << 16);
}
__device__ __forceinline__ float fdot2_(unsigned h, unsigned w, float c) {
#if __has_builtin(__builtin_amdgcn_fdot2)
    return __builtin_amdgcn_fdot2(__builtin_bit_cast(h2v, h), __builtin_bit_cast(h2v, w), c, false);
#else
    h2v H = __builtin_bit_cast(h2v, h), W = __builtin_bit_cast(h2v, w);
    return c + (float)H[0] * (float)W[0] + (float)H[1] * (float)W[1];
#endif
}
__device__ __forceinline__ float plo_(unsigned u) { return (float)__builtin_bit_cast(h2v, u)[0]; }
__device__ __forceinline__ float phi_(unsigned u) { return (float)__builtin_bit_cast(h2v, u)[1]; }
__device__ __forceinline__ half8 ld8h_(const unsigned short* p) {
    return __builtin_bit_cast(half8, *(const short8*)p);
}

// ================= fused precompute #1: sbase + combine_frag_tiled + bias + pack =================
// bid ranges: [0,512) sbase | [512,752) tiled combine | [752,1136) bias | [1136,1598) pack
__global__ __launch_bounds__(256) void precompute1_kernel(
    const float* __restrict__ emb, float* __restrict__ Sb,
    const float* __restrict__ gW, const float* __restrict__ uW,
    unsigned short* __restrict__ WgF, unsigned short* __restrict__ WuF,
    const float* __restrict__ gb, const float* __restrict__ ub,
    float* __restrict__ bgc, float* __restrict__ buc,
    const float* __restrict__ Wih0, const float* __restrict__ Whh0,
    const float* __restrict__ Wih1, const float* __restrict__ Whh1,
    unsigned* __restrict__ wp_ih0, unsigned* __restrict__ wp_hh0,
    unsigned* __restrict__ wp_ih1, unsigned* __restrict__ wp_hh1) {
    __shared__ float poolS[EMBD * 512];
    __shared__ float embS[128 * EMBD];
    __shared__ float redw[4];
    const int bid = blockIdx.x;
    const int tid = threadIdx.x;
    if (bid < 512) {
        // ---- sbase (block = row n) ----
        const int n = bid;
        float* en = embS;   // reuse LDS
        if (tid < EMBD) en[tid] = emb[n * EMBD + tid];
        __syncthreads();
        float v[2];
        #pragma unroll
        for (int q = 0; q < 2; q++) {
            int m = tid + q * 256;
            float s = 0.f;
            #pragma unroll
            for (int d = 0; d < EMBD; d++) s += en[d] * emb[m * EMBD + d];
            v[q] = fmaxf(s, 0.f);
        }
        float mx = fmaxf(v[0], v[1]);
        for (int off = 32; off >= 1; off >>= 1) mx = fmaxf(mx, __shfl_xor(mx, off));
        if ((tid & 63) == 0) redw[tid >> 6] = mx;
        __syncthreads();
        mx = fmaxf(fmaxf(redw[0], redw[1]), fmaxf(redw[2], redw[3]));
        __syncthreads();
        v[0] = __expf(v[0] - mx);
        v[1] = __expf(v[1] - mx);
        float sm = v[0] + v[1];
        for (int off = 32; off >= 1; off >>= 1) sm += __shfl_xor(sm, off);
        if ((tid & 63) == 0) redw[tid >> 6] = sm;
        __syncthreads();
        sm = redw[0] + redw[1] + redw[2] + redw[3];
        float inv = 1.f / sm;
        Sb[n * NN + tid]       = v[0] * inv;
        Sb[n * NN + tid + 256] = v[1] * inv;
        return;
    }
    if (bid < 752) {
        // ---- tiled combine (240 blocks) ----
        const int bb = bid - 512;
        const int group = bb % 60;
        const int chunk = bb / 60;
        const float* pool;
        unsigned short* outU;
        int OT, Ow, ot, kc;
        if (group < 40) { pool = gW; outU = WgF; Ow = 128; OT = 8; ot = group / 5; kc = group % 5; }
        else { int g2 = group - 40; pool = uW; outU = WuF; Ow = 64; OT = 4; ot = g2 / 5; kc = g2 % 5; }
        for (int l = tid; l < EMBD * 512; l += 256) {
            int d = l >> 9, rem = l & 511;
            int kpl = rem >> 4, ol = rem & 15;
            int kp = kc * 32 + kpl;
            float v = 0.f;
            if (kp < 2 * CIN) v = pool[((size_t)d * (2 * CIN) + kp) * Ow + ot * 16 + ol];
            poolS[l] = v;
        }
        for (int l = tid; l < 128 * EMBD; l += 256) {
            int nl = l / EMBD, d = l - nl * EMBD;
            embS[l] = emb[(chunk * 128 + nl) * EMBD + d];
        }
        __syncthreads();
        const int e0 = tid * 2, e1 = e0 + 1;
        const int l0 = e0 >> 3, j0 = e0 & 7, p0 = (((l0 >> 4) << 3) + j0) * 16 + (l0 & 15);
        const int l1 = e1 >> 3, j1 = e1 & 7, p1 = (((l1 >> 4) << 3) + j1) * 16 + (l1 & 15);
        float w0[EMBD], w1[EMBD];
        #pragma unroll
        for (int d = 0; d < EMBD; d++) {
            w0[d] = poolS[d * 512 + p0];
            w1[d] = poolS[d * 512 + p1];
        }
        for (int nl = 0; nl < 128; nl++) {
            int n = chunk * 128 + nl;
            float a0 = 0.f, a1 = 0.f;
            #pragma unroll
            for (int d = 0; d < EMBD; d++) {
                float e = embS[nl * EMBD + d];
                a0 += e * w0[d];
                a1 += e * w1[d];
            }
            size_t base = (((size_t)n * OT + ot) * 5 + kc) * 512;
            *(unsigned*)(outU + base + e0) = pkh_(a0, a1);
        }
        return;
    }
    if (bid < 1136) {
        // ---- biases (384 blocks) ----
        int idx = (bid - 752) * 256 + tid;
        if (idx < NN * 128) {
            int n = idx >> 7, rem = idx & 127;
            float a = 0.f;
            #pragma unroll
            for (int d = 0; d < EMBD; d++) a += emb[n * EMBD + d] * gb[d * 128 + rem];
            bgc[idx] = a;
        } else if (idx < NN * 128 + NN * 64) {
            int j = idx - NN * 128;
            int n = j >> 6, rem = j & 63;
            float a = 0.f;
            #pragma unroll
            for (int d = 0; d < EMBD; d++) a += emb[n * EMBD + d] * ub[d * 64 + rem];
            buc[j] = a;
        }
        return;
    }
    {
        // ---- pack LSTM weights (462 blocks) ----
        int idx = (bid - 1136) * 256 + tid;
        const float* w;
        unsigned* wp;
        int K, base;
        if (idx < 16640)       { w = Wih0; wp = wp_ih0; K = 64;  base = 0; }
        else if (idx < 50440)  { w = Whh0; wp = wp_hh0; K = 130; base = 16640; }
        else if (idx < 84240)  { w = Wih1; wp = wp_ih1; K = 130; base = 50440; }
        else if (idx < 118040) { w = Whh1; wp = wp_hh1; K = 130; base = 84240; }
        else return;
        int j2 = idx - base;
        int kk = j2 / LG, j = j2 - kk * LG;
        wp[j2] = pkh_(w[j * K + 2 * kk], w[j * K + 2 * kk + 1]);
    }
}

// ------------- LSTM body (proven code, b as parameter) -------------
__device__ void lstm_body(int b, int tid,
    const float* __restrict__ sr,
    const unsigned* __restrict__ wp_ih0, const float* __restrict__ Wih0,
    const float* __restrict__ bih0, const float* __restrict__ bhh0,
    const unsigned* __restrict__ wp_hh0, const float* __restrict__ Whh0,
    const unsigned* __restrict__ wp_ih1, const float* __restrict__ Wih1,
    const float* __restrict__ bih1, const float* __restrict__ bhh1,
    const unsigned* __restrict__ wp_hh1, const float* __restrict__ Whh1,
    float* __restrict__ h2last) {
    const int lane = tid & 63;
    const int wv = tid >> 6;
    __shared__ __align__(16) float xp[32 * 520];
    __shared__ __align__(16) unsigned h1p[32 * 68];
    __shared__ __align__(16) float h1s[32 * 132];
    __shared__ __align__(16) unsigned xsp[32 * 32];
    __shared__ __align__(16) unsigned hP[68];
    __shared__ __align__(16) float hS[132], cS[132];
    __shared__ float gS[520];
    __shared__ float WeX[130 * 8];
    unsigned wpk[65];

    for (int l = tid; l < 32 * 32; l += 512) {
        float2 v = *(const float2*)&sr[(size_t)b * 2048 + 2 * l];
        xsp[l] = pkh_(v.x, v.y);
    }
    #pragma unroll
    for (int kk = 0; kk < 32; kk++) wpk[kk] = wp_ih0[kk * 520 + tid];
    for (int l = tid; l < 64 * 8; l += 512) { int k = l >> 3, je = l & 7; WeX[l] = Wih0[(512 + je) * 64 + k]; }
    __syncthreads();
    {
        float bias = bih0[tid] + bhh0[tid];
        for (int t = 0; t < 32; t++) {
            const uint4* x4 = (const uint4*)&xsp[t * 32];
            float a0 = bias, a1 = 0.f;
            #pragma unroll
            for (int q = 0; q < 8; q++) {
                uint4 hq = x4[q];
                a0 = fdot2_(hq.x, wpk[4 * q + 0], a0);
                a1 = fdot2_(hq.y, wpk[4 * q + 1], a1);
                a0 = fdot2_(hq.z, wpk[4 * q + 2], a0);
                a1 = fdot2_(hq.w, wpk[4 * q + 3], a1);
            }
            xp[t * 520 + tid] = a0 + a1;
        }
        if (tid < 256) {
            int je = tid & 7, t = tid >> 3;
            float a = bih0[512 + je] + bhh0[512 + je];
            for (int p = 0; p < 32; p++) {
                unsigned u = xsp[t * 32 + p];
                a += plo_(u) * WeX[(2 * p) * 8 + je] + phi_(u) * WeX[(2 * p + 1) * 8 + je];
            }
            xp[t * 520 + 512 + je] = a;
        }
    }
    __syncthreads();

    #pragma unroll
    for (int kk = 0; kk < 65; kk++) wpk[kk] = wp_hh0[kk * 520 + tid];
    for (int l = tid; l < 130 * 8; l += 512) { int k = l >> 3, je = l & 7; WeX[l] = Whh0[(512 + je) * 130 + k]; }
    for (int l = tid; l < 132; l += 512) { hS[l] = 0.f; cS[l] = 0.f; }
    if (tid < 68) hP[tid] = 0u;
    __syncthreads();
    {
        float we0 = WeX[lane * 8 + wv];
        float we1 = WeX[(lane + 64) * 8 + wv];
        float we2 = (lane < 2) ? WeX[(lane + 128) * 8 + wv] : 0.f;
        for (int t = 0; t < 32; t++) {
            const uint4* hp4 = (const uint4*)hP;
            float a0 = xp[t * 520 + tid], a1 = 0.f;
            #pragma unroll
            for (int q = 0; q < 16; q++) {
                uint4 hq = hp4[q];
                a0 = fdot2_(hq.x, wpk[4 * q + 0], a0);
                a1 = fdot2_(hq.y, wpk[4 * q + 1], a1);
                a0 = fdot2_(hq.z, wpk[4 * q + 2], a0);
                a1 = fdot2_(hq.w, wpk[4 * q + 3], a1);
            }
            a0 = fdot2_(hP[64], wpk[64], a0);
            gS[tid] = a0 + a1;
            float p = hS[lane] * we0 + hS[lane + 64] * we1;
            if (lane < 2) p += hS[lane + 128] * we2;
            #pragma unroll
            for (int off = 32; off >= 1; off >>= 1) p += __shfl_xor(p, off);
            if (lane == 0) gS[512 + wv] = xp[t * 520 + 512 + wv] + p;
            __syncthreads();
            if (tid < 130) {
                float iv = sigmoidf_(gS[tid]);
                float fv = sigmoidf_(gS[130 + tid]);
                float gv = tanhf_(gS[260 + tid]);
                float ov = sigmoidf_(gS[390 + tid]);
                float cv = fv * cS[tid] + iv * gv;
                cS[tid] = cv;
                float hv = ov * tanhf_(cv);
                hS[tid] = hv;
                h1s[t * 132 + tid] = hv;
                float nb = __shfl_xor(hv, 1);
                if ((tid & 1) == 0) {
                    unsigned pk = pkh_(hv, nb);
                    hP[tid >> 1] = pk;
                    h1p[t * 68 + (tid >> 1)] = pk;
                }
            }
            __syncthreads();
        }
    }

    #pragma unroll
    for (int kk = 0; kk < 65; kk++) wpk[kk] = wp_ih1[kk * 520 + tid];
    for (int l = tid; l < 130 * 8; l += 512) { int k = l >> 3, je = l & 7; WeX[l] = Wih1[(512 + je) * 130 + k]; }
    __syncthreads();
    {
        float bias = bih1[tid] + bhh1[tid];
        for (int t = 0; t < 32; t++) {
            const uint4* x4 = (const uint4*)&h1p[t * 68];
            float a0 = bias, a1 = 0.f;
            #pragma unroll
            for (int q = 0; q < 16; q++) {
                uint4 hq = x4[q];
                a0 = fdot2_(hq.x, wpk[4 * q + 0], a0);
                a1 = fdot2_(hq.y, wpk[4 * q + 1], a1);
                a0 = fdot2_(hq.z, wpk[4 * q + 2], a0);
                a1 = fdot2_(hq.w, wpk[4 * q + 3], a1);
            }
            a0 = fdot2_(h1p[t * 68 + 64], wpk[64], a0);
            xp[t * 520 + tid] = a0 + a1;
        }
        if (tid < 256) {
            int je = tid & 7, t = tid >> 3;
            float a = bih1[512 + je] + bhh1[512 + je];
            for (int k = 0; k < 130; k++) a += h1s[t * 132 + k] * WeX[k * 8 + je];
            xp[t * 520 + 512 + je] = a;
        }
    }
    __syncthreads();

    #pragma unroll
    for (int kk = 0; kk < 65; kk++) wpk[kk] = wp_hh1[kk * 520 + tid];
    for (int l = tid; l < 130 * 8; l += 512) { int k = l >> 3, je = l & 7; WeX[l] = Whh1[(512 + je) * 130 + k]; }
    for (int l = tid; l < 132; l += 512) { hS[l] = 0.f; cS[l] = 0.f; }
    if (tid < 68) hP[tid] = 0u;
    __syncthreads();
    {
        float we0 = WeX[lane * 8 + wv];
        float we1 = WeX[(lane + 64) * 8 + wv];
        float we2 = (lane < 2) ? WeX[(lane + 128) * 8 + wv] : 0.f;
        for (int t = 0; t < 32; t++) {
            const uint4* hp4 = (const uint4*)hP;
            float a0 = xp[t * 520 + tid], a1 = 0.f;
            #pragma unroll
            for (int q = 0; q < 16; q++) {
                uint4 hq = hp4[q];
                a0 = fdot2_(hq.x, wpk[4 * q + 0], a0);
                a1 = fdot2_(hq.y, wpk[4 * q + 1], a1);
                a0 = fdot2_(hq.z, wpk[4 * q + 2], a0);
                a1 = fdot2_(hq.w, wpk[4 * q + 3], a1);
            }
            a0 = fdot2_(hP[64], wpk[64], a0);
            gS[tid] = a0 + a1;
            float p = hS[lane] * we0 + hS[lane + 64] * we1;
            if (lane < 2) p += hS[lane + 128] * we2;
            #pragma unroll
            for (int off = 32; off >= 1; off >>= 1) p += __shfl_xor(p, off);
            if (lane == 0) gS[512 + wv] = xp[t * 520 + 512 + wv] + p;
            __syncthreads();
            if (tid < 130) {
                float iv = sigmoidf_(gS[tid]);
                float fv = sigmoidf_(gS[130 + tid]);
                float gv = tanhf_(gS[260 + tid]);
                float ov = sigmoidf_(gS[390 + tid]);
                float cv = fv * cS[tid] + iv * gv;
                cS[tid] = cv;
                float hv = ov * tanhf_(cv);
                hS[tid] = hv;
                float nb = __shfl_xor(hv, 1);
                if ((tid & 1) == 0) hP[tid >> 1] = pkh_(hv, nb);
                if (t == 31) h2last[(size_t)b * LH + tid] = hv;
            }
            __syncthreads();
        }
    }
}

// ------------- mega precompute: lstm (16) + xfrag-t0 (160) + state-zero (1024) + afrag (12288) -------------
__global__ __launch_bounds__(512) void mega_kernel(
    const float* __restrict__ Sb, const float* __restrict__ mask,
    unsigned short* __restrict__ AF,
    const float* __restrict__ ent, unsigned short* __restrict__ Xf,
    float* __restrict__ state,
    const float* __restrict__ sr,
    const unsigned* __restrict__ wp_ih0, const float* __restrict__ Wih0,
    const float* __restrict__ bih0, const float* __restrict__ bhh0,
    const unsigned* __restrict__ wp_hh0, const float* __restrict__ Whh0,
    const unsigned* __restrict__ wp_ih1, const float* __restrict__ Wih1,
    const float* __restrict__ bih1, const float* __restrict__ bhh1,
    const unsigned* __restrict__ wp_hh1, const float* __restrict__ Whh1,
    float* __restrict__ h2last) {
    const int bid = blockIdx.x;
    const int tid = threadIdx.x;
    if (bid < 16) {
        lstm_body(bid, tid, sr, wp_ih0, Wih0, bih0, bhh0, wp_hh0, Whh0,
                  wp_ih1, Wih1, bih1, bhh1, wp_hh1, Whh1, h2last);
        return;
    }
    if (bid < 176) {
        int idx = (bid - 16) * 512 + tid;
        int l = idx & 63;
        int r = idx >> 6;
        int kc = r & 1; r >>= 1;
        int ct = r % 5; r /= 5;
        int q = r & 7;
        int b = r >> 3;
        const int c = ct * 16 + (l & 15);
        const int mbase = q * 64 + kc * 32 + ((l >> 4) & 3) * 8;
        union { unsigned short u[8]; short8 v; } o;
        #pragma unroll
        for (int j = 0; j < 8; j++) {
            int m = mbase + j;
            float v = 0.f;
            if (c < DINV) v = ent[((size_t)(b * TT + 0) * NN + m) * DINV + c];
            o.u[j] = f16u_(v);
        }
        size_t base = ((((size_t)b * 8 + q) * 5 + ct) * 2 + kc) * 512;
        *(short8*)(Xf + base + l * 8) = o.v;
        return;
    }
    if (bid < 1200) {
        int i = (bid - 176) * 512 + tid;
        state[i] = 0.f;
        return;
    }
    size_t idx = (size_t)(bid - 1200) * 512 + tid;
    int l = (int)(idx & 63);
    size_t f = idx >> 6;
    int mch = (int)(f & 15); f >>= 4;
    int ntile = (int)(f & 31); f >>= 5;
    int t = (int)(f % 12);
    int b = (int)(f / 12);
    int nrow = ntile * 16 + (l & 15);
    int m0 = mch * 32 + ((l >> 4) & 3) * 8;
    const float4* s4 = (const float4*)(Sb + (size_t)nrow * NN + m0);
    const float4* m4 = (const float4*)(mask + ((size_t)(b * TT + t) * NN + nrow) * NN + m0);
    float4 sa = s4[0], sc = s4[1];
    float4 ma = m4[0], mc = m4[1];
    union { unsigned short u[8]; short8 v; } o;
    o.u[0] = f16u_(sa.x * ma.x); o.u[1] = f16u_(sa.y * ma.y);
    o.u[2] = f16u_(sa.z * ma.z); o.u[3] = f16u_(sa.w * ma.w);
    o.u[4] = f16u_(sc.x * mc.x); o.u[5] = f16u_(sc.y * mc.y);
    o.u[6] = f16u_(sc.z * mc.z); o.u[7] = f16u_(sc.w * mc.w);
    *(short8*)(AF + idx * 8) = o.v;
}

// ------------- spmm: pure f16 MFMA, no LDS, no barriers. grid (8, 16, 2) -------------
__global__ __launch_bounds__(256) void spmm_kernel(const unsigned short* __restrict__ AF,
                                                   const unsigned short* __restrict__ Xf,
                                                   float* __restrict__ out, int t) {
    const int tid = threadIdx.x;
    const int lane = tid & 63;
    const int w = tid >> 6;
    const int b = blockIdx.y;
    const int z = blockIdx.z;
    float* __restrict__ outp = out + (size_t)z * PART;
    const int ntile = blockIdx.x * 4 + w;

    f32x4 acc[5];
    #pragma unroll
    for (int ct = 0; ct < 5; ct++) acc[ct] = (f32x4){0.f, 0.f, 0.f, 0.f};

    #pragma unroll
    for (int r2 = 0; r2 < 4; r2++) {
        #pragma unroll
        for (int kc = 0; kc < 2; kc++) {
            const int mch = z * 8 + r2 * 2 + kc;
            const int q = z * 4 + r2;
            half8 a = ld8h_(AF + ((((size_t)b * TT + t) * 32 + ntile) * 16 + mch) * 512 + lane * 8);
            #pragma unroll
            for (int ct = 0; ct < 5; ct++) {
                half8 bf = ld8h_(Xf + ((((size_t)b * 8 + q) * 5 + ct) * 2 + kc) * 512 + lane * 8);
                acc[ct] = __builtin_amdgcn_mfma_f32_16x16x32_f16(a, bf, acc[ct], 0, 0, 0);
            }
        }
    }
    const int col = lane & 15, rq = lane >> 4;
    #pragma unroll
    for (int ct = 0; ct < 5; ct++) {
        int c = ct * 16 + col;
        if (c < CIN) {
            #pragma unroll
            for (int reg = 0; reg < 4; reg++) {
                int n = ntile * 16 + rq * 4 + reg;
                outp[(size_t)b * NN * CIN + n * CIN + c] = acc[ct][reg];
            }
        }
    }
}

// ------------- gate via f16 MFMA; writes cand-frags into Xf -------------
__global__ __launch_bounds__(256) void gate_mfma_kernel(const float* __restrict__ ent,
                                                        const float* __restrict__ state,
                                                        const float* __restrict__ xg1,
                                                        const unsigned short* __restrict__ WgF,
                                                        const float* __restrict__ bg,
                                                        float* __restrict__ cand,
                                                        float* __restrict__ rbuf,
                                                        unsigned short* __restrict__ Xf,
                                                        int t) {
    __shared__ unsigned short A_h[16 * 168];
    const int n = blockIdx.x;
    const int tid = threadIdx.x;
    const int lane = tid & 63;
    const int w = tid >> 6;
    for (int idx = tid; idx < 16 * 36; idx += 256) {
        int b = idx / 36, k = 132 + idx - b * 36;
        A_h[b * 168 + k] = 0;
    }
    for (int idx = tid; idx < 16 * 132; idx += 256) {
        int b = idx / 132, ip = idx - b * 132;
        float v;
        if (ip < CIN) {
            v = (ip < DINV) ? ent[((size_t)(b * TT + t) * NN + n) * DINV + ip]
                            : state[((size_t)b * NN + n) * HH + (ip - DINV)];
        } else {
            size_t g = (size_t)b * NN * CIN + n * CIN + (ip - CIN);
            v = xg1[g] + xg1[g + PART];
        }
        A_h[b * 168 + ip] = f16u_(v);
    }
    __syncthreads();

    f32x4 acc0 = {0.f, 0.f, 0.f, 0.f}, acc1 = {0.f, 0.f, 0.f, 0.f};
    const unsigned short* Wn = WgF + (size_t)n * (8 * 5 * 512);
    #pragma unroll
    for (int kc = 0; kc < 5; kc++) {
        int aoff = (lane & 15) * 168 + kc * 32 + (lane >> 4) * 8;
        half8 ah = ld8h_(&A_h[aoff]);
        half8 bh0 = ld8h_(Wn + ((size_t)(w * 5) + kc) * 512 + lane * 8);
        half8 bh1 = ld8h_(Wn + ((size_t)((w + 4) * 5) + kc) * 512 + lane * 8);
        acc0 = __builtin_amdgcn_mfma_f32_16x16x32_f16(ah, bh0, acc0, 0, 0, 0);
        acc1 = __builtin_amdgcn_mfma_f32_16x16x32_f16(ah, bh1, acc1, 0, 0, 0);
    }
    const int col = lane & 15, rq = lane >> 4;
    const int q = n >> 6, kcn = (n >> 5) & 1, jn = n & 7;
    {
        int o = w * 16 + col;
        int c = o + DINV;
        int ct = c >> 4, cl = c & 15;
        int l = ((n >> 3) & 3) * 16 + cl;
        float bias = bg[n * 128 + o];
        #pragma unroll
        for (int reg = 0; reg < 4; reg++) {
            int b = rq * 4 + reg;
            float zr = sigmoidf_(acc0[reg] + bias);
            float val = zr * state[((size_t)b * NN + n) * HH + o];
            cand[(size_t)b * NN * CIN + n * CIN + c] = val;
            size_t fb = ((((size_t)b * 8 + q) * 5 + ct) * 2 + kcn) * 512;
            Xf[fb + l * 8 + jn] = f16u_(val);
        }
    }
    {
        int o = (w + 4) * 16 + col;
        float bias = bg[n * 128 + o];
        #pragma unroll
        for (int reg = 0; reg < 4; reg++) {
            int b = rq * 4 + reg;
            float zr = sigmoidf_(acc1[reg] + bias);
            rbuf[((size_t)b * NN + n) * HH + (o - HH)] = zr;
        }
    }
    if (tid < 32) {
        int b = tid >> 1, i = tid & 1;
        cand[(size_t)b * NN * CIN + n * CIN + i] =
            ent[((size_t)(b * TT + t) * NN + n) * DINV + i];
    }
}

// ------------- update via f16 MFMA; writes state + state-frags + ent_{t+1}-frags -------------
__global__ __launch_bounds__(256) void update_mfma_kernel(const float* __restrict__ cand,
                                                          const float* __restrict__ xg2,
                                                          const unsigned short* __restrict__ WuF,
                                                          const float* __restrict__ bu,
                                                          const float* __restrict__ rbuf,
                                                          float* __restrict__ state,
                                                          unsigned short* __restrict__ Xf,
                                                          const float* __restrict__ ent,
                                                          int tnext) {
    __shared__ unsigned short A_h[16 * 168];
    const int n = blockIdx.x;
    const int tid = threadIdx.x;
    const int lane = tid & 63;
    const int w = tid >> 6;
    for (int idx = tid; idx < 16 * 36; idx += 256) {
        int b = idx / 36, k = 132 + idx - b * 36;
        A_h[b * 168 + k] = 0;
    }
    for (int idx = tid; idx < 16 * 132; idx += 256) {
        int b = idx / 132, ip = idx - b * 132;
        float v;
        if (ip < CIN) {
            v = cand[(size_t)b * NN * CIN + n * CIN + ip];
        } else {
            size_t g = (size_t)b * NN * CIN + n * CIN + (ip - CIN);
            v = xg2[g] + xg2[g + PART];
        }
        A_h[b * 168 + ip] = f16u_(v);
    }
    __syncthreads();

    f32x4 acc = {0.f, 0.f, 0.f, 0.f};
    const unsigned short* Wn = WuF + (size_t)n * (4 * 5 * 512);
    #pragma unroll
    for (int kc = 0; kc < 5; kc++) {
        int aoff = (lane & 15) * 168 + kc * 32 + (lane >> 4) * 8;
        half8 ah = ld8h_(&A_h[aoff]);
        half8 bh = ld8h_(Wn + ((size_t)(w * 5) + kc) * 512 + lane * 8);
        acc = __builtin_amdgcn_mfma_f32_16x16x32_f16(ah, bh, acc, 0, 0, 0);
    }
    const int col = lane & 15, rq = lane >> 4;
    const int q = n >> 6, kcn = (n >> 5) & 1, jn = n & 7;
    int o = w * 16 + col;
    int c = o + DINV;
    int ct = c >> 4, cl = c & 15;
    int l = ((n >> 3) & 3) * 16 + cl;
    float bias = bu[n * HH + o];
    #pragma unroll
    for (int reg = 0; reg < 4; reg++) {
        int b = rq * 4 + reg;
        float hc = tanhf_(acc[reg] + bias);
        size_t g = ((size_t)b * NN + n) * HH + o;
        float rr = rbuf[g];
        float ns = rr * state[g] + (1.f - rr) * hc;
        state[g] = ns;
        size_t fb = ((((size_t)b * 8 + q) * 5 + ct) * 2 + kcn) * 512;
        Xf[fb + l * 8 + jn] = f16u_(ns);
    }
    if (w == 0 && col < DINV && tnext < TT) {
        int le = ((n >> 3) & 3) * 16 + col;
        #pragma unroll
        for (int reg = 0; reg < 4; reg++) {
            int b = rq * 4 + reg;
            float v = ent[((size_t)(b * TT + tnext) * NN + n) * DINV + col];
            size_t fb = ((((size_t)b * 8 + q) * 5 + 0) * 2 + kcn) * 512;
            Xf[fb + le * 8 + jn] = f16u_(v);
        }
    }
}

// ------------- final -------------
__global__ __launch_bounds__(256) void final_kernel(const float* __restrict__ state,
                                                    const float* __restrict__ h2last,
                                                    const float* __restrict__ fcW,
                                                    const float* __restrict__ fcb,
                                                    float* __restrict__ out) {
    const int b = blockIdx.x;
    const int tid = threadIdx.x;
    __shared__ float feat[LH + HH];
    __shared__ float red[4][HH];
    const int hh = tid & 63, q = tid >> 6;
    float mx = -INFINITY;
    for (int n = q * 128; n < q * 128 + 128; n++)
        mx = fmaxf(mx, state[((size_t)b * NN + n) * HH + hh]);
    red[q][hh] = mx;
    if (tid >= 64 && tid < 64 + LH)
        feat[tid - 64] = h2last[(size_t)b * LH + (tid - 64)];
    __syncthreads();
    if (tid < HH)
        feat[LH + tid] = fmaxf(fmaxf(red[0][tid], red[1][tid]), fmaxf(red[2][tid], red[3][tid]));
    __syncthreads();
    if (tid < 24) {
        float a = fcb[tid];
        for (int k = 0; k < LH + HH; k++) a += feat[k] * fcW[tid * (LH + HH) + k];
        out[b * 24 + tid] = sigmoidf_(a);
    }
}

extern "C" void kernel_launch(void* const* d_in, const int* in_sizes, int n_in,
                              void* d_out, int out_size, void* d_ws, size_t ws_size,
                              hipStream_t stream) {
    const float* ent  = (const float*)d_in[0];
    const float* mask = (const float*)d_in[1];
    const float* sr   = (const float*)d_in[2];
    const float* emb  = (const float*)d_in[3];
    const float* gW   = (const float*)d_in[4];
    const float* gb   = (const float*)d_in[5];
    const float* uW   = (const float*)d_in[6];
    const float* ub   = (const float*)d_in[7];
    const float* Wih0 = (const float*)d_in[8];
    const float* Whh0 = (const float*)d_in[9];
    const float* bih0 = (const float*)d_in[10];
    const float* bhh0 = (const float*)d_in[11];
    const float* Wih1 = (const float*)d_in[12];
    const float* Whh1 = (const float*)d_in[13];
    const float* bih1 = (const float*)d_in[14];
    const float* bhh1 = (const float*)d_in[15];
    const float* fcW  = (const float*)d_in[16];
    const float* fcb  = (const float*)d_in[17];
    float* out = (float*)d_out;
    float* ws = (float*)d_ws;

    size_t off = 0;
    float* Sb     = ws + off; off += (size_t)NN * NN;
    unsigned short* WgF = (unsigned short*)(ws + off); off += (size_t)NN * 8 * 5 * 256;
    unsigned short* WuF = (unsigned short*)(ws + off); off += (size_t)NN * 4 * 5 * 256;
    unsigned short* AF  = (unsigned short*)(ws + off); off += (size_t)BB * TT * 32 * 16 * 256;
    float* bgc    = ws + off; off += (size_t)NN * 128;
    float* buc    = ws + off; off += (size_t)NN * HH;
    float* state  = ws + off; off += (size_t)BB * NN * HH;
    float* xgP    = ws + off; off += 2 * PART;
    float* cand   = ws + off; off += PART;
    float* rbuf   = ws + off; off += (size_t)BB * NN * HH;
    float* h2last = ws + off; off += (size_t)BB * LH;
    unsigned short* Xf = (unsigned short*)(ws + off); off += (size_t)BB * 8 * 5 * 2 * 256;
    unsigned* wp_ih0 = (unsigned*)(ws + off); off += 32 * LG;
    unsigned* wp_hh0 = (unsigned*)(ws + off); off += 65 * LG;
    unsigned* wp_ih1 = (unsigned*)(ws + off); off += 65 * LG;
    unsigned* wp_hh1 = (unsigned*)(ws + off); off += 65 * LG;

    // ---- precompute (2 dispatches) ----
    precompute1_kernel<<<1598, 256, 0, stream>>>(emb, Sb, gW, uW, WgF, WuF, gb, ub, bgc, buc,
                                                 Wih0, Whh0, Wih1, Whh1,
                                                 wp_ih0, wp_hh0, wp_ih1, wp_hh1);
    mega_kernel<<<13488, 512, 0, stream>>>(Sb, mask, AF, ent, Xf, state, sr,
                                           wp_ih0, Wih0, bih0, bhh0, wp_hh0, Whh0,
                                           wp_ih1, Wih1, bih1, bhh1, wp_hh1, Whh1, h2last);

    // ---- GRU over 12 timesteps (4 dispatches each) ----
    for (int t = 0; t < TT; t++) {
        spmm_kernel<<<dim3(8, BB, 2), 256, 0, stream>>>(AF, Xf, xgP, t);
        gate_mfma_kernel<<<NN, 256, 0, stream>>>(ent, state, xgP, WgF, bgc, cand, rbuf, Xf, t);
        spmm_kernel<<<dim3(8, BB, 2), 256, 0, stream>>>(AF, Xf, xgP, t);
        update_mfma_kernel<<<NN, 256, 0, stream>>>(cand, xgP, WuF, buc, rbuf, state, Xf, ent, t + 1);
    }

    // ---- final ----
    final_kernel<<<BB, 256, 0, stream>>>(state, h2last, fcW, fcb, out);
}

// Round 17
// 642.815 us; speedup vs baseline: 1.0343x; 1.0343x over previous
//
#include <hip/hip_runtime.h>
#include <math.h>

#define NN 512
#define EMBD 10
#define HH 64
#define DINV 2
#define CIN 66
#define TT 12
#define BB 16
#define LH 130
#define LG 520
#define PART ((size_t)BB * NN * CIN)

typedef __attribute__((ext_vector_type(8))) short short8;
typedef __attribute__((ext_vector_type(8))) _Float16 half8;
typedef __attribute__((ext_vector_type(4))) float f32x4;
typedef __attribute__((ext_vector_type(2))) _Float16 h2v;

__device__ __forceinline__ float sigmoidf_(float x) { return 1.f / (1.f + __expf(-x)); }
__device__ __forceinline__ float tanhf_(float x)    { return 1.f - 2.f / (1.f + __expf(2.f * x)); }
__device__ __forceinline__ unsigned short f16u_(float v) {
    return __builtin_bit_cast(unsigned short, (_Float16)v);
}
__device__ __forceinline__ unsigned pkh_(float a, float b) {
    return (unsigned)f16u_(a) | ((unsigned)f16u_(b) << 16);
}
__device__ __forceinline__ float fdot2_(unsigned h, unsigned w, float c) {
#if __has_builtin(__builtin_amdgcn_fdot2)
    return __builtin_amdgcn_fdot2(__builtin_bit_cast(h2v, h), __builtin_bit_cast(h2v, w), c, false);
#else
    h2v H = __builtin_bit_cast(h2v, h), W = __builtin_bit_cast(h2v, w);
    return c + (float)H[0] * (float)W[0] + (float)H[1] * (float)W[1];
#endif
}
__device__ __forceinline__ float plo_(unsigned u) { return (float)__builtin_bit_cast(h2v, u)[0]; }
__device__ __forceinline__ float phi_(unsigned u) { return (float)__builtin_bit_cast(h2v, u)[1]; }
__device__ __forceinline__ half8 ld8h_(const unsigned short* p) {
    return __builtin_bit_cast(half8, *(const short8*)p);
}

// ================= fused precompute #1: sbase + combine_frag_tiled + bias + pack =================
__global__ __launch_bounds__(256) void precompute1_kernel(
    const float* __restrict__ emb, float* __restrict__ Sb,
    const float* __restrict__ gW, const float* __restrict__ uW,
    unsigned short* __restrict__ WgF, unsigned short* __restrict__ WuF,
    const float* __restrict__ gb, const float* __restrict__ ub,
    float* __restrict__ bgc, float* __restrict__ buc,
    const float* __restrict__ Wih0, const float* __restrict__ Whh0,
    const float* __restrict__ Wih1, const float* __restrict__ Whh1,
    unsigned* __restrict__ wp_ih0, unsigned* __restrict__ wp_hh0,
    unsigned* __restrict__ wp_ih1, unsigned* __restrict__ wp_hh1) {
    __shared__ float poolS[EMBD * 512];
    __shared__ float embS[128 * EMBD];
    __shared__ float redw[4];
    const int bid = blockIdx.x;
    const int tid = threadIdx.x;
    if (bid < 512) {
        const int n = bid;
        float* en = embS;
        if (tid < EMBD) en[tid] = emb[n * EMBD + tid];
        __syncthreads();
        float v[2];
        #pragma unroll
        for (int q = 0; q < 2; q++) {
            int m = tid + q * 256;
            float s = 0.f;
            #pragma unroll
            for (int d = 0; d < EMBD; d++) s += en[d] * emb[m * EMBD + d];
            v[q] = fmaxf(s, 0.f);
        }
        float mx = fmaxf(v[0], v[1]);
        for (int off = 32; off >= 1; off >>= 1) mx = fmaxf(mx, __shfl_xor(mx, off));
        if ((tid & 63) == 0) redw[tid >> 6] = mx;
        __syncthreads();
        mx = fmaxf(fmaxf(redw[0], redw[1]), fmaxf(redw[2], redw[3]));
        __syncthreads();
        v[0] = __expf(v[0] - mx);
        v[1] = __expf(v[1] - mx);
        float sm = v[0] + v[1];
        for (int off = 32; off >= 1; off >>= 1) sm += __shfl_xor(sm, off);
        if ((tid & 63) == 0) redw[tid >> 6] = sm;
        __syncthreads();
        sm = redw[0] + redw[1] + redw[2] + redw[3];
        float inv = 1.f / sm;
        Sb[n * NN + tid]       = v[0] * inv;
        Sb[n * NN + tid + 256] = v[1] * inv;
        return;
    }
    if (bid < 752) {
        const int bb = bid - 512;
        const int group = bb % 60;
        const int chunk = bb / 60;
        const float* pool;
        unsigned short* outU;
        int OT, Ow, ot, kc;
        if (group < 40) { pool = gW; outU = WgF; Ow = 128; OT = 8; ot = group / 5; kc = group % 5; }
        else { int g2 = group - 40; pool = uW; outU = WuF; Ow = 64; OT = 4; ot = g2 / 5; kc = g2 % 5; }
        for (int l = tid; l < EMBD * 512; l += 256) {
            int d = l >> 9, rem = l & 511;
            int kpl = rem >> 4, ol = rem & 15;
            int kp = kc * 32 + kpl;
            float v = 0.f;
            if (kp < 2 * CIN) v = pool[((size_t)d * (2 * CIN) + kp) * Ow + ot * 16 + ol];
            poolS[l] = v;
        }
        for (int l = tid; l < 128 * EMBD; l += 256) {
            int nl = l / EMBD, d = l - nl * EMBD;
            embS[l] = emb[(chunk * 128 + nl) * EMBD + d];
        }
        __syncthreads();
        const int e0 = tid * 2, e1 = e0 + 1;
        const int l0 = e0 >> 3, j0 = e0 & 7, p0 = (((l0 >> 4) << 3) + j0) * 16 + (l0 & 15);
        const int l1 = e1 >> 3, j1 = e1 & 7, p1 = (((l1 >> 4) << 3) + j1) * 16 + (l1 & 15);
        float w0[EMBD], w1[EMBD];
        #pragma unroll
        for (int d = 0; d < EMBD; d++) {
            w0[d] = poolS[d * 512 + p0];
            w1[d] = poolS[d * 512 + p1];
        }
        for (int nl = 0; nl < 128; nl++) {
            int n = chunk * 128 + nl;
            float a0 = 0.f, a1 = 0.f;
            #pragma unroll
            for (int d = 0; d < EMBD; d++) {
                float e = embS[nl * EMBD + d];
                a0 += e * w0[d];
                a1 += e * w1[d];
            }
            size_t base = (((size_t)n * OT + ot) * 5 + kc) * 512;
            *(unsigned*)(outU + base + e0) = pkh_(a0, a1);
        }
        return;
    }
    if (bid < 1136) {
        int idx = (bid - 752) * 256 + tid;
        if (idx < NN * 128) {
            int n = idx >> 7, rem = idx & 127;
            float a = 0.f;
            #pragma unroll
            for (int d = 0; d < EMBD; d++) a += emb[n * EMBD + d] * gb[d * 128 + rem];
            bgc[idx] = a;
        } else if (idx < NN * 128 + NN * 64) {
            int j = idx - NN * 128;
            int n = j >> 6, rem = j & 63;
            float a = 0.f;
            #pragma unroll
            for (int d = 0; d < EMBD; d++) a += emb[n * EMBD + d] * ub[d * 64 + rem];
            buc[j] = a;
        }
        return;
    }
    {
        int idx = (bid - 1136) * 256 + tid;
        const float* w;
        unsigned* wp;
        int K, base;
        if (idx < 16640)       { w = Wih0; wp = wp_ih0; K = 64;  base = 0; }
        else if (idx < 50440)  { w = Whh0; wp = wp_hh0; K = 130; base = 16640; }
        else if (idx < 84240)  { w = Wih1; wp = wp_ih1; K = 130; base = 50440; }
        else if (idx < 118040) { w = Whh1; wp = wp_hh1; K = 130; base = 84240; }
        else return;
        int j2 = idx - base;
        int kk = j2 / LG, j = j2 - kk * LG;
        wp[j2] = pkh_(w[j * K + 2 * kk], w[j * K + 2 * kk + 1]);
    }
}

// ------------- LSTM body (proven code, b as parameter) -------------
__device__ void lstm_body(int b, int tid,
    const float* __restrict__ sr,
    const unsigned* __restrict__ wp_ih0, const float* __restrict__ Wih0,
    const float* __restrict__ bih0, const float* __restrict__ bhh0,
    const unsigned* __restrict__ wp_hh0, const float* __restrict__ Whh0,
    const unsigned* __restrict__ wp_ih1, const float* __restrict__ Wih1,
    const float* __restrict__ bih1, const float* __restrict__ bhh1,
    const unsigned* __restrict__ wp_hh1, const float* __restrict__ Whh1,
    float* __restrict__ h2last) {
    const int lane = tid & 63;
    const int wv = tid >> 6;
    __shared__ __align__(16) float xp[32 * 520];
    __shared__ __align__(16) unsigned h1p[32 * 68];
    __shared__ __align__(16) float h1s[32 * 132];
    __shared__ __align__(16) unsigned xsp[32 * 32];
    __shared__ __align__(16) unsigned hP[68];
    __shared__ __align__(16) float hS[132], cS[132];
    __shared__ float gS[520];
    __shared__ float WeX[130 * 8];
    unsigned wpk[65];

    for (int l = tid; l < 32 * 32; l += 512) {
        float2 v = *(const float2*)&sr[(size_t)b * 2048 + 2 * l];
        xsp[l] = pkh_(v.x, v.y);
    }
    #pragma unroll
    for (int kk = 0; kk < 32; kk++) wpk[kk] = wp_ih0[kk * 520 + tid];
    for (int l = tid; l < 64 * 8; l += 512) { int k = l >> 3, je = l & 7; WeX[l] = Wih0[(512 + je) * 64 + k]; }
    __syncthreads();
    {
        float bias = bih0[tid] + bhh0[tid];
        for (int t = 0; t < 32; t++) {
            const uint4* x4 = (const uint4*)&xsp[t * 32];
            float a0 = bias, a1 = 0.f;
            #pragma unroll
            for (int q = 0; q < 8; q++) {
                uint4 hq = x4[q];
                a0 = fdot2_(hq.x, wpk[4 * q + 0], a0);
                a1 = fdot2_(hq.y, wpk[4 * q + 1], a1);
                a0 = fdot2_(hq.z, wpk[4 * q + 2], a0);
                a1 = fdot2_(hq.w, wpk[4 * q + 3], a1);
            }
            xp[t * 520 + tid] = a0 + a1;
        }
        if (tid < 256) {
            int je = tid & 7, t = tid >> 3;
            float a = bih0[512 + je] + bhh0[512 + je];
            for (int p = 0; p < 32; p++) {
                unsigned u = xsp[t * 32 + p];
                a += plo_(u) * WeX[(2 * p) * 8 + je] + phi_(u) * WeX[(2 * p + 1) * 8 + je];
            }
            xp[t * 520 + 512 + je] = a;
        }
    }
    __syncthreads();

    #pragma unroll
    for (int kk = 0; kk < 65; kk++) wpk[kk] = wp_hh0[kk * 520 + tid];
    for (int l = tid; l < 130 * 8; l += 512) { int k = l >> 3, je = l & 7; WeX[l] = Whh0[(512 + je) * 130 + k]; }
    for (int l = tid; l < 132; l += 512) { hS[l] = 0.f; cS[l] = 0.f; }
    if (tid < 68) hP[tid] = 0u;
    __syncthreads();
    {
        float we0 = WeX[lane * 8 + wv];
        float we1 = WeX[(lane + 64) * 8 + wv];
        float we2 = (lane < 2) ? WeX[(lane + 128) * 8 + wv] : 0.f;
        for (int t = 0; t < 32; t++) {
            const uint4* hp4 = (const uint4*)hP;
            float a0 = xp[t * 520 + tid], a1 = 0.f;
            #pragma unroll
            for (int q = 0; q < 16; q++) {
                uint4 hq = hp4[q];
                a0 = fdot2_(hq.x, wpk[4 * q + 0], a0);
                a1 = fdot2_(hq.y, wpk[4 * q + 1], a1);
                a0 = fdot2_(hq.z, wpk[4 * q + 2], a0);
                a1 = fdot2_(hq.w, wpk[4 * q + 3], a1);
            }
            a0 = fdot2_(hP[64], wpk[64], a0);
            gS[tid] = a0 + a1;
            float p = hS[lane] * we0 + hS[lane + 64] * we1;
            if (lane < 2) p += hS[lane + 128] * we2;
            #pragma unroll
            for (int off = 32; off >= 1; off >>= 1) p += __shfl_xor(p, off);
            if (lane == 0) gS[512 + wv] = xp[t * 520 + 512 + wv] + p;
            __syncthreads();
            if (tid < 130) {
                float iv = sigmoidf_(gS[tid]);
                float fv = sigmoidf_(gS[130 + tid]);
                float gv = tanhf_(gS[260 + tid]);
                float ov = sigmoidf_(gS[390 + tid]);
                float cv = fv * cS[tid] + iv * gv;
                cS[tid] = cv;
                float hv = ov * tanhf_(cv);
                hS[tid] = hv;
                h1s[t * 132 + tid] = hv;
                float nb = __shfl_xor(hv, 1);
                if ((tid & 1) == 0) {
                    unsigned pk = pkh_(hv, nb);
                    hP[tid >> 1] = pk;
                    h1p[t * 68 + (tid >> 1)] = pk;
                }
            }
            __syncthreads();
        }
    }

    #pragma unroll
    for (int kk = 0; kk < 65; kk++) wpk[kk] = wp_ih1[kk * 520 + tid];
    for (int l = tid; l < 130 * 8; l += 512) { int k = l >> 3, je = l & 7; WeX[l] = Wih1[(512 + je) * 130 + k]; }
    __syncthreads();
    {
        float bias = bih1[tid] + bhh1[tid];
        for (int t = 0; t < 32; t++) {
            const uint4* x4 = (const uint4*)&h1p[t * 68];
            float a0 = bias, a1 = 0.f;
            #pragma unroll
            for (int q = 0; q < 16; q++) {
                uint4 hq = x4[q];
                a0 = fdot2_(hq.x, wpk[4 * q + 0], a0);
                a1 = fdot2_(hq.y, wpk[4 * q + 1], a1);
                a0 = fdot2_(hq.z, wpk[4 * q + 2], a0);
                a1 = fdot2_(hq.w, wpk[4 * q + 3], a1);
            }
            a0 = fdot2_(h1p[t * 68 + 64], wpk[64], a0);
            xp[t * 520 + tid] = a0 + a1;
        }
        if (tid < 256) {
            int je = tid & 7, t = tid >> 3;
            float a = bih1[512 + je] + bhh1[512 + je];
            for (int k = 0; k < 130; k++) a += h1s[t * 132 + k] * WeX[k * 8 + je];
            xp[t * 520 + 512 + je] = a;
        }
    }
    __syncthreads();

    #pragma unroll
    for (int kk = 0; kk < 65; kk++) wpk[kk] = wp_hh1[kk * 520 + tid];
    for (int l = tid; l < 130 * 8; l += 512) { int k = l >> 3, je = l & 7; WeX[l] = Whh1[(512 + je) * 130 + k]; }
    for (int l = tid; l < 132; l += 512) { hS[l] = 0.f; cS[l] = 0.f; }
    if (tid < 68) hP[tid] = 0u;
    __syncthreads();
    {
        float we0 = WeX[lane * 8 + wv];
        float we1 = WeX[(lane + 64) * 8 + wv];
        float we2 = (lane < 2) ? WeX[(lane + 128) * 8 + wv] : 0.f;
        for (int t = 0; t < 32; t++) {
            const uint4* hp4 = (const uint4*)hP;
            float a0 = xp[t * 520 + tid], a1 = 0.f;
            #pragma unroll
            for (int q = 0; q < 16; q++) {
                uint4 hq = hp4[q];
                a0 = fdot2_(hq.x, wpk[4 * q + 0], a0);
                a1 = fdot2_(hq.y, wpk[4 * q + 1], a1);
                a0 = fdot2_(hq.z, wpk[4 * q + 2], a0);
                a1 = fdot2_(hq.w, wpk[4 * q + 3], a1);
            }
            a0 = fdot2_(hP[64], wpk[64], a0);
            gS[tid] = a0 + a1;
            float p = hS[lane] * we0 + hS[lane + 64] * we1;
            if (lane < 2) p += hS[lane + 128] * we2;
            #pragma unroll
            for (int off = 32; off >= 1; off >>= 1) p += __shfl_xor(p, off);
            if (lane == 0) gS[512 + wv] = xp[t * 520 + 512 + wv] + p;
            __syncthreads();
            if (tid < 130) {
                float iv = sigmoidf_(gS[tid]);
                float fv = sigmoidf_(gS[130 + tid]);
                float gv = tanhf_(gS[260 + tid]);
                float ov = sigmoidf_(gS[390 + tid]);
                float cv = fv * cS[tid] + iv * gv;
                cS[tid] = cv;
                float hv = ov * tanhf_(cv);
                hS[tid] = hv;
                float nb = __shfl_xor(hv, 1);
                if ((tid & 1) == 0) hP[tid >> 1] = pkh_(hv, nb);
                if (t == 31) h2last[(size_t)b * LH + tid] = hv;
            }
            __syncthreads();
        }
    }
}

// ------------- mega precompute: lstm (16) + xfrag-t0 (160) + state-zero (1024) + afrag (12288) -------------
__global__ __launch_bounds__(512) void mega_kernel(
    const float* __restrict__ Sb, const float* __restrict__ mask,
    unsigned short* __restrict__ AF,
    const float* __restrict__ ent, unsigned short* __restrict__ Xf,
    float* __restrict__ state,
    const float* __restrict__ sr,
    const unsigned* __restrict__ wp_ih0, const float* __restrict__ Wih0,
    const float* __restrict__ bih0, const float* __restrict__ bhh0,
    const unsigned* __restrict__ wp_hh0, const float* __restrict__ Whh0,
    const unsigned* __restrict__ wp_ih1, const float* __restrict__ Wih1,
    const float* __restrict__ bih1, const float* __restrict__ bhh1,
    const unsigned* __restrict__ wp_hh1, const float* __restrict__ Whh1,
    float* __restrict__ h2last) {
    const int bid = blockIdx.x;
    const int tid = threadIdx.x;
    if (bid < 16) {
        lstm_body(bid, tid, sr, wp_ih0, Wih0, bih0, bhh0, wp_hh0, Whh0,
                  wp_ih1, Wih1, bih1, bhh1, wp_hh1, Whh1, h2last);
        return;
    }
    if (bid < 176) {
        int idx = (bid - 16) * 512 + tid;
        int l = idx & 63;
        int r = idx >> 6;
        int kc = r & 1; r >>= 1;
        int ct = r % 5; r /= 5;
        int q = r & 7;
        int b = r >> 3;
        const int c = ct * 16 + (l & 15);
        const int mbase = q * 64 + kc * 32 + ((l >> 4) & 3) * 8;
        union { unsigned short u[8]; short8 v; } o;
        #pragma unroll
        for (int j = 0; j < 8; j++) {
            int m = mbase + j;
            float v = 0.f;
            if (c < DINV) v = ent[((size_t)(b * TT + 0) * NN + m) * DINV + c];
            o.u[j] = f16u_(v);
        }
        size_t base = ((((size_t)b * 8 + q) * 5 + ct) * 2 + kc) * 512;
        *(short8*)(Xf + base + l * 8) = o.v;
        return;
    }
    if (bid < 1200) {
        int i = (bid - 176) * 512 + tid;
        state[i] = 0.f;
        return;
    }
    size_t idx = (size_t)(bid - 1200) * 512 + tid;
    int l = (int)(idx & 63);
    size_t f = idx >> 6;
    int mch = (int)(f & 15); f >>= 4;
    int ntile = (int)(f & 31); f >>= 5;
    int t = (int)(f % 12);
    int b = (int)(f / 12);
    int nrow = ntile * 16 + (l & 15);
    int m0 = mch * 32 + ((l >> 4) & 3) * 8;
    const float4* s4 = (const float4*)(Sb + (size_t)nrow * NN + m0);
    const float4* m4 = (const float4*)(mask + ((size_t)(b * TT + t) * NN + nrow) * NN + m0);
    float4 sa = s4[0], sc = s4[1];
    float4 ma = m4[0], mc = m4[1];
    union { unsigned short u[8]; short8 v; } o;
    o.u[0] = f16u_(sa.x * ma.x); o.u[1] = f16u_(sa.y * ma.y);
    o.u[2] = f16u_(sa.z * ma.z); o.u[3] = f16u_(sa.w * ma.w);
    o.u[4] = f16u_(sc.x * mc.x); o.u[5] = f16u_(sc.y * mc.y);
    o.u[6] = f16u_(sc.z * mc.z); o.u[7] = f16u_(sc.w * mc.w);
    *(short8*)(AF + idx * 8) = o.v;
}

// ------------- spmm: pure f16 MFMA, no LDS, no barriers. grid (8, 16, 4) -------------
__global__ __launch_bounds__(256) void spmm_kernel(const unsigned short* __restrict__ AF,
                                                   const unsigned short* __restrict__ Xf,
                                                   float* __restrict__ out, int t) {
    const int tid = threadIdx.x;
    const int lane = tid & 63;
    const int w = tid >> 6;
    const int b = blockIdx.y;
    const int z = blockIdx.z;
    float* __restrict__ outp = out + (size_t)z * PART;
    const int ntile = blockIdx.x * 4 + w;

    f32x4 acc[5];
    #pragma unroll
    for (int ct = 0; ct < 5; ct++) acc[ct] = (f32x4){0.f, 0.f, 0.f, 0.f};

    #pragma unroll
    for (int r2 = 0; r2 < 2; r2++) {
        #pragma unroll
        for (int kc = 0; kc < 2; kc++) {
            const int mch = z * 4 + r2 * 2 + kc;
            const int q = z * 2 + r2;
            half8 a = ld8h_(AF + ((((size_t)b * TT + t) * 32 + ntile) * 16 + mch) * 512 + lane * 8);
            #pragma unroll
            for (int ct = 0; ct < 5; ct++) {
                half8 bf = ld8h_(Xf + ((((size_t)b * 8 + q) * 5 + ct) * 2 + kc) * 512 + lane * 8);
                acc[ct] = __builtin_amdgcn_mfma_f32_16x16x32_f16(a, bf, acc[ct], 0, 0, 0);
            }
        }
    }
    const int col = lane & 15, rq = lane >> 4;
    #pragma unroll
    for (int ct = 0; ct < 5; ct++) {
        int c = ct * 16 + col;
        if (c < CIN) {
            #pragma unroll
            for (int reg = 0; reg < 4; reg++) {
                int n = ntile * 16 + rq * 4 + reg;
                outp[(size_t)b * NN * CIN + n * CIN + c] = acc[ct][reg];
            }
        }
    }
}

// ------------- gate via f16 MFMA; writes cand-frags into Xf -------------
__global__ __launch_bounds__(256) void gate_mfma_kernel(const float* __restrict__ ent,
                                                        const float* __restrict__ state,
                                                        const float* __restrict__ xg1,
                                                        const unsigned short* __restrict__ WgF,
                                                        const float* __restrict__ bg,
                                                        float* __restrict__ cand,
                                                        float* __restrict__ rbuf,
                                                        unsigned short* __restrict__ Xf,
                                                        int t) {
    __shared__ unsigned short A_h[16 * 168];
    const int n = blockIdx.x;
    const int tid = threadIdx.x;
    const int lane = tid & 63;
    const int w = tid >> 6;
    for (int idx = tid; idx < 16 * 36; idx += 256) {
        int b = idx / 36, k = 132 + idx - b * 36;
        A_h[b * 168 + k] = 0;
    }
    for (int idx = tid; idx < 16 * 132; idx += 256) {
        int b = idx / 132, ip = idx - b * 132;
        float v;
        if (ip < CIN) {
            v = (ip < DINV) ? ent[((size_t)(b * TT + t) * NN + n) * DINV + ip]
                            : state[((size_t)b * NN + n) * HH + (ip - DINV)];
        } else {
            size_t g = (size_t)b * NN * CIN + n * CIN + (ip - CIN);
            v = xg1[g] + xg1[g + PART] + xg1[g + 2 * PART] + xg1[g + 3 * PART];
        }
        A_h[b * 168 + ip] = f16u_(v);
    }
    __syncthreads();

    f32x4 acc0 = {0.f, 0.f, 0.f, 0.f}, acc1 = {0.f, 0.f, 0.f, 0.f};
    const unsigned short* Wn = WgF + (size_t)n * (8 * 5 * 512);
    #pragma unroll
    for (int kc = 0; kc < 5; kc++) {
        int aoff = (lane & 15) * 168 + kc * 32 + (lane >> 4) * 8;
        half8 ah = ld8h_(&A_h[aoff]);
        half8 bh0 = ld8h_(Wn + ((size_t)(w * 5) + kc) * 512 + lane * 8);
        half8 bh1 = ld8h_(Wn + ((size_t)((w + 4) * 5) + kc) * 512 + lane * 8);
        acc0 = __builtin_amdgcn_mfma_f32_16x16x32_f16(ah, bh0, acc0, 0, 0, 0);
        acc1 = __builtin_amdgcn_mfma_f32_16x16x32_f16(ah, bh1, acc1, 0, 0, 0);
    }
    const int col = lane & 15, rq = lane >> 4;
    const int q = n >> 6, kcn = (n >> 5) & 1, jn = n & 7;
    {
        int o = w * 16 + col;
        int c = o + DINV;
        int ct = c >> 4, cl = c & 15;
        int l = ((n >> 3) & 3) * 16 + cl;
        float bias = bg[n * 128 + o];
        #pragma unroll
        for (int reg = 0; reg < 4; reg++) {
            int b = rq * 4 + reg;
            float zr = sigmoidf_(acc0[reg] + bias);
            float val = zr * state[((size_t)b * NN + n) * HH + o];
            cand[(size_t)b * NN * CIN + n * CIN + c] = val;
            size_t fb = ((((size_t)b * 8 + q) * 5 + ct) * 2 + kcn) * 512;
            Xf[fb + l * 8 + jn] = f16u_(val);
        }
    }
    {
        int o = (w + 4) * 16 + col;
        float bias = bg[n * 128 + o];
        #pragma unroll
        for (int reg = 0; reg < 4; reg++) {
            int b = rq * 4 + reg;
            float zr = sigmoidf_(acc1[reg] + bias);
            rbuf[((size_t)b * NN + n) * HH + (o - HH)] = zr;
        }
    }
    if (tid < 32) {
        int b = tid >> 1, i = tid & 1;
        cand[(size_t)b * NN * CIN + n * CIN + i] =
            ent[((size_t)(b * TT + t) * NN + n) * DINV + i];
    }
}

// ------------- update via f16 MFMA; writes state + state-frags + ent_{t+1}-frags -------------
__global__ __launch_bounds__(256) void update_mfma_kernel(const float* __restrict__ cand,
                                                          const float* __restrict__ xg2,
                                                          const unsigned short* __restrict__ WuF,
                                                          const float* __restrict__ bu,
                                                          const float* __restrict__ rbuf,
                                                          float* __restrict__ state,
                                                          unsigned short* __restrict__ Xf,
                                                          const float* __restrict__ ent,
                                                          int tnext) {
    __shared__ unsigned short A_h[16 * 168];
    const int n = blockIdx.x;
    const int tid = threadIdx.x;
    const int lane = tid & 63;
    const int w = tid >> 6;
    for (int idx = tid; idx < 16 * 36; idx += 256) {
        int b = idx / 36, k = 132 + idx - b * 36;
        A_h[b * 168 + k] = 0;
    }
    for (int idx = tid; idx < 16 * 132; idx += 256) {
        int b = idx / 132, ip = idx - b * 132;
        float v;
        if (ip < CIN) {
            v = cand[(size_t)b * NN * CIN + n * CIN + ip];
        } else {
            size_t g = (size_t)b * NN * CIN + n * CIN + (ip - CIN);
            v = xg2[g] + xg2[g + PART] + xg2[g + 2 * PART] + xg2[g + 3 * PART];
        }
        A_h[b * 168 + ip] = f16u_(v);
    }
    __syncthreads();

    f32x4 acc = {0.f, 0.f, 0.f, 0.f};
    const unsigned short* Wn = WuF + (size_t)n * (4 * 5 * 512);
    #pragma unroll
    for (int kc = 0; kc < 5; kc++) {
        int aoff = (lane & 15) * 168 + kc * 32 + (lane >> 4) * 8;
        half8 ah = ld8h_(&A_h[aoff]);
        half8 bh = ld8h_(Wn + ((size_t)(w * 5) + kc) * 512 + lane * 8);
        acc = __builtin_amdgcn_mfma_f32_16x16x32_f16(ah, bh, acc, 0, 0, 0);
    }
    const int col = lane & 15, rq = lane >> 4;
    const int q = n >> 6, kcn = (n >> 5) & 1, jn = n & 7;
    int o = w * 16 + col;
    int c = o + DINV;
    int ct = c >> 4, cl = c & 15;
    int l = ((n >> 3) & 3) * 16 + cl;
    float bias = bu[n * HH + o];
    #pragma unroll
    for (int reg = 0; reg < 4; reg++) {
        int b = rq * 4 + reg;
        float hc = tanhf_(acc[reg] + bias);
        size_t g = ((size_t)b * NN + n) * HH + o;
        float rr = rbuf[g];
        float ns = rr * state[g] + (1.f - rr) * hc;
        state[g] = ns;
        size_t fb = ((((size_t)b * 8 + q) * 5 + ct) * 2 + kcn) * 512;
        Xf[fb + l * 8 + jn] = f16u_(ns);
    }
    if (w == 0 && col < DINV && tnext < TT) {
        int le = ((n >> 3) & 3) * 16 + col;
        #pragma unroll
        for (int reg = 0; reg < 4; reg++) {
            int b = rq * 4 + reg;
            float v = ent[((size_t)(b * TT + tnext) * NN + n) * DINV + col];
            size_t fb = ((((size_t)b * 8 + q) * 5 + 0) * 2 + kcn) * 512;
            Xf[fb + le * 8 + jn] = f16u_(v);
        }
    }
}

// ------------- final -------------
__global__ __launch_bounds__(256) void final_kernel(const float* __restrict__ state,
                                                    const float* __restrict__ h2last,
                                                    const float* __restrict__ fcW,
                                                    const float* __restrict__ fcb,
                                                    float* __restrict__ out) {
    const int b = blockIdx.x;
    const int tid = threadIdx.x;
    __shared__ float feat[LH + HH];
    __shared__ float red[4][HH];
    const int hh = tid & 63, q = tid >> 6;
    float mx = -INFINITY;
    for (int n = q * 128; n < q * 128 + 128; n++)
        mx = fmaxf(mx, state[((size_t)b * NN + n) * HH + hh]);
    red[q][hh] = mx;
    if (tid >= 64 && tid < 64 + LH)
        feat[tid - 64] = h2last[(size_t)b * LH + (tid - 64)];
    __syncthreads();
    if (tid < HH)
        feat[LH + tid] = fmaxf(fmaxf(red[0][tid], red[1][tid]), fmaxf(red[2][tid], red[3][tid]));
    __syncthreads();
    if (tid < 24) {
        float a = fcb[tid];
        for (int k = 0; k < LH + HH; k++) a += feat[k] * fcW[tid * (LH + HH) + k];
        out[b * 24 + tid] = sigmoidf_(a);
    }
}

extern "C" void kernel_launch(void* const* d_in, const int* in_sizes, int n_in,
                              void* d_out, int out_size, void* d_ws, size_t ws_size,
                              hipStream_t stream) {
    const float* ent  = (const float*)d_in[0];
    const float* mask = (const float*)d_in[1];
    const float* sr   = (const float*)d_in[2];
    const float* emb  = (const float*)d_in[3];
    const float* gW   = (const float*)d_in[4];
    const float* gb   = (const float*)d_in[5];
    const float* uW   = (const float*)d_in[6];
    const float* ub   = (const float*)d_in[7];
    const float* Wih0 = (const float*)d_in[8];
    const float* Whh0 = (const float*)d_in[9];
    const float* bih0 = (const float*)d_in[10];
    const float* bhh0 = (const float*)d_in[11];
    const float* Wih1 = (const float*)d_in[12];
    const float* Whh1 = (const float*)d_in[13];
    const float* bih1 = (const float*)d_in[14];
    const float* bhh1 = (const float*)d_in[15];
    const float* fcW  = (const float*)d_in[16];
    const float* fcb  = (const float*)d_in[17];
    float* out = (float*)d_out;
    float* ws = (float*)d_ws;

    size_t off = 0;
    float* Sb     = ws + off; off += (size_t)NN * NN;
    unsigned short* WgF = (unsigned short*)(ws + off); off += (size_t)NN * 8 * 5 * 256;
    unsigned short* WuF = (unsigned short*)(ws + off); off += (size_t)NN * 4 * 5 * 256;
    unsigned short* AF  = (unsigned short*)(ws + off); off += (size_t)BB * TT * 32 * 16 * 256;
    float* bgc    = ws + off; off += (size_t)NN * 128;
    float* buc    = ws + off; off += (size_t)NN * HH;
    float* state  = ws + off; off += (size_t)BB * NN * HH;
    float* xgP    = ws + off; off += 4 * PART;
    float* cand   = ws + off; off += PART;
    float* rbuf   = ws + off; off += (size_t)BB * NN * HH;
    float* h2last = ws + off; off += (size_t)BB * LH;
    unsigned short* Xf = (unsigned short*)(ws + off); off += (size_t)BB * 8 * 5 * 2 * 256;
    unsigned* wp_ih0 = (unsigned*)(ws + off); off += 32 * LG;
    unsigned* wp_hh0 = (unsigned*)(ws + off); off += 65 * LG;
    unsigned* wp_ih1 = (unsigned*)(ws + off); off += 65 * LG;
    unsigned* wp_hh1 = (unsigned*)(ws + off); off += 65 * LG;

    // ---- precompute (2 dispatches) ----
    precompute1_kernel<<<1598, 256, 0, stream>>>(emb, Sb, gW, uW, WgF, WuF, gb, ub, bgc, buc,
                                                 Wih0, Whh0, Wih1, Whh1,
                                                 wp_ih0, wp_hh0, wp_ih1, wp_hh1);
    mega_kernel<<<13488, 512, 0, stream>>>(Sb, mask, AF, ent, Xf, state, sr,
                                           wp_ih0, Wih0, bih0, bhh0, wp_hh0, Whh0,
                                           wp_ih1, Wih1, bih1, bhh1, wp_hh1, Whh1, h2last);

    // ---- GRU over 12 timesteps (4 dispatches each) ----
    for (int t = 0; t < TT; t++) {
        spmm_kernel<<<dim3(8, BB, 4), 256, 0, stream>>>(AF, Xf, xgP, t);
        gate_mfma_kernel<<<NN, 256, 0, stream>>>(ent, state, xgP, WgF, bgc, cand, rbuf, Xf, t);
        spmm_kernel<<<dim3(8, BB, 4), 256, 0, stream>>>(AF, Xf, xgP, t);
        update_mfma_kernel<<<NN, 256, 0, stream>>>(cand, xgP, WuF, buc, rbuf, state, Xf, ent, t + 1);
    }

    // ---- final ----
    final_kernel<<<BB, 256, 0, stream>>>(state, h2last, fcW, fcb, out);
}